// Round 9
// baseline (187.201 us; speedup 1.0000x reference)
//
#include <hip/hip_runtime.h>

#define HID 128
#define CHUNK 16384      // edges per histogram chunk (power of 2)
#define CSHIFT 14
#define MAXW 25088       // LDS packed-pair words (supports N <= 50176), 100 KB

typedef unsigned short u16;
typedef unsigned int u32;

__device__ __forceinline__ float bf2f(u16 u) { return __uint_as_float(((u32)u) << 16); }
__device__ __forceinline__ float lof(u32 w) { return __uint_as_float(w << 16); }
__device__ __forceinline__ float hif(u32 w) { return __uint_as_float(w & 0xFFFF0000u); }
__device__ __forceinline__ u16 f2bf(float f) {
    u32 x = __float_as_uint(f);
    return (u16)((x + 0x7FFF + ((x >> 16) & 1)) >> 16);  // RNE
}

// ---- per-chunk LDS histogram over ALL nodes (packed u16 pairs) + local edge rank ----
__global__ __launch_bounds__(1024) void hist_kernel(const int* __restrict__ ei,
        u32* __restrict__ Hp, u16* __restrict__ lrank, int E, int W) {
    __shared__ u32 hcnt[MAXW];
    int c = blockIdx.x;
    for (int j = threadIdx.x; j < W; j += 1024) hcnt[j] = 0;
    __syncthreads();
    int beg = c << CSHIFT;
    int end = min(E, beg + CHUNK);
    for (int i = beg + (int)threadIdx.x; i < end; i += 1024) {
        int d = ei[E + i];
        u32 sh = (u32)(d & 1) << 4;               // 0 or 16
        u32 old = atomicAdd(&hcnt[d >> 1], 1u << sh);
        lrank[i] = (u16)((old >> sh) & 0xFFFFu);  // low half can't carry: count<=16384
    }
    __syncthreads();
    for (int j = threadIdx.x; j < W; j += 1024) Hp[(size_t)c * W + j] = hcnt[j];
}

// ---- convert Hp to exclusive cumulative-over-chunks (in place), emit node totals t ----
__global__ void scan_node_kernel(u32* __restrict__ Hp, u32* __restrict__ t,
                                 int W, int NB, int N) {
    int j = blockIdx.x * blockDim.x + threadIdx.x;
    if (j >= W) return;
    u32 lo = 0, hi = 0;
    for (int c = 0; c < NB; c++) {
        size_t idx = (size_t)c * W + j;
        u32 w = Hp[idx];
        Hp[idx] = lo | (hi << 16);     // bases fit u16 (deg <= 65535)
        lo += w & 0xFFFFu;
        hi += w >> 16;
    }
    int n0 = 2 * j, n1 = 2 * j + 1;
    if (n0 < N) t[n0] = lo;
    if (n1 < N) t[n1] = hi;
}

// ---- single-block exclusive scan of node totals -> offsets (replaces scanA+scanC) ----
__global__ __launch_bounds__(1024) void scanOne_kernel(const u32* __restrict__ t,
        int* __restrict__ offsets, int N, int E) {
    __shared__ int sdata[1024];
    int tid = threadIdx.x;
    int per = (N + 1023) / 1024;
    int beg = tid * per;
    int end = min(N, beg + per);
    int s = 0;
    for (int i = beg; i < end; i++) s += (int)t[i];
    sdata[tid] = s;
    __syncthreads();
    for (int off = 1; off < 1024; off <<= 1) {
        int x = sdata[tid];
        int y = (tid >= off) ? sdata[tid - off] : 0;
        __syncthreads();
        sdata[tid] = x + y;
        __syncthreads();
    }
    int excl = sdata[tid] - s;
    for (int i = beg; i < end; i++) {
        offsets[i] = excl;
        excl += (int)t[i];
    }
    if (tid == 1023) offsets[N] = E;
}

// ---- fused pack (k*0.25,v -> bf16 rows) + scatter (atomic-free), range-split ----
__global__ void packscatter_kernel(const float* __restrict__ k, const float* __restrict__ v,
                                   u16* __restrict__ kv, const int* __restrict__ ei,
                                   const u32* __restrict__ Hp, const u16* __restrict__ lrank,
                                   const int* __restrict__ offsets, u16* __restrict__ srcs,
                                   int N, int E, int W, int packBlocks) {
    if ((int)blockIdx.x < packBlocks) {
        int g = blockIdx.x * 256 + threadIdx.x;   // node*64 + lane
        int node = g >> 6, l = g & 63;
        if (node >= N) return;
        float2 kk = ((const float2*)(k + (long long)node * HID))[l];
        float2 vv = ((const float2*)(v + (long long)node * HID))[l];
        ushort4 o;
        o.x = f2bf(kk.x * 0.25f);   // fold 1/SCALE (exact pow2) into k
        o.y = f2bf(kk.y * 0.25f);
        o.z = f2bf(vv.x);
        o.w = f2bf(vv.y);
        ((ushort4*)(kv + (long long)node * 256))[l] = o;
    } else {
        int e = (blockIdx.x - packBlocks) * 256 + threadIdx.x;
        if (e >= E) return;
        int c = e >> CSHIFT;
        int d = ei[E + e];
        u32 sh = (u32)(d & 1) << 4;
        u32 b = (Hp[(size_t)c * W + (d >> 1)] >> sh) & 0xFFFFu;
        int pos = offsets[d] + (int)b + (int)lrank[e];
        srcs[pos] = (u16)ei[e];
    }
}

// ---- per-node reduction: 4 dims/lane, 2 edges/wave-step, 2 nodes/block ----
__global__ __launch_bounds__(128) void reduce_packed(
        const float* __restrict__ q, const u16* __restrict__ kv,
        const int* __restrict__ offsets, const u16* __restrict__ srcs,
        float* __restrict__ out, int N) {
    int node = blockIdx.x * 2 + (threadIdx.x >> 6);
    if (node >= N) return;
    int l = threadIdx.x & 63;
    int m = l & 31;          // 4-dim group within the row
    int half = l >> 5;       // which edge of the pair this lane handles

    float4 qv = ((const float4*)(q + (long long)node * HID))[m];
    const char* kvb = (const char*)kv;
    u32 laneoff = (u32)m << 4;   // 16B per group
    float4 acc = make_float4(0.0f, 0.0f, 0.0f, 0.0f);
    float z = 0.0f;

    int beg = offsets[node];
    int end = offsets[node + 1];
    int i = beg;

#define GLOAD(s_) (*(const uint4*)(kvb + (((u32)(s_) << 9) + laneoff)))

    for (; i + 8 <= end; i += 8) {
        u32 sA0 = srcs[i + 0], sB0 = srcs[i + 1];
        u32 sA1 = srcs[i + 2], sB1 = srcs[i + 3];
        u32 sA2 = srcs[i + 4], sB2 = srcs[i + 5];
        u32 sA3 = srcs[i + 6], sB3 = srcs[i + 7];
        uint4 a0 = GLOAD(half ? sB0 : sA0);
        uint4 a1 = GLOAD(half ? sB1 : sA1);
        uint4 a2 = GLOAD(half ? sB2 : sA2);
        uint4 a3 = GLOAD(half ? sB3 : sA3);

        float p0 = lof(a0.x) * qv.x + hif(a0.x) * qv.y + lof(a0.z) * qv.z + hif(a0.z) * qv.w;
        float p1 = lof(a1.x) * qv.x + hif(a1.x) * qv.y + lof(a1.z) * qv.z + hif(a1.z) * qv.w;
        float p2 = lof(a2.x) * qv.x + hif(a2.x) * qv.y + lof(a2.z) * qv.z + hif(a2.z) * qv.w;
        float p3 = lof(a3.x) * qv.x + hif(a3.x) * qv.y + lof(a3.z) * qv.z + hif(a3.z) * qv.w;

        p0 += __shfl_xor(p0, 1); p1 += __shfl_xor(p1, 1);
        p2 += __shfl_xor(p2, 1); p3 += __shfl_xor(p3, 1);
        p0 += __shfl_xor(p0, 2); p1 += __shfl_xor(p1, 2);
        p2 += __shfl_xor(p2, 2); p3 += __shfl_xor(p3, 2);

        float c0 = __expf(fminf(fmaxf(p0, -5.0f), 5.0f));
        float c1 = __expf(fminf(fmaxf(p1, -5.0f), 5.0f));
        float c2 = __expf(fminf(fmaxf(p2, -5.0f), 5.0f));
        float c3 = __expf(fminf(fmaxf(p3, -5.0f), 5.0f));

        acc.x += lof(a0.y) * c0 + lof(a1.y) * c1 + lof(a2.y) * c2 + lof(a3.y) * c3;
        acc.y += hif(a0.y) * c0 + hif(a1.y) * c1 + hif(a2.y) * c2 + hif(a3.y) * c3;
        acc.z += lof(a0.w) * c0 + lof(a1.w) * c1 + lof(a2.w) * c2 + lof(a3.w) * c3;
        acc.w += hif(a0.w) * c0 + hif(a1.w) * c1 + hif(a2.w) * c2 + hif(a3.w) * c3;
        z += c0 + c1 + c2 + c3;
    }
    for (; i < end; i += 2) {
        int idx = i + half;
        bool ok = idx < end;
        u32 s = srcs[ok ? idx : i];
        uint4 a = GLOAD(s);
        float p = lof(a.x) * qv.x + hif(a.x) * qv.y + lof(a.z) * qv.z + hif(a.z) * qv.w;
        p += __shfl_xor(p, 1);
        p += __shfl_xor(p, 2);
        float c = __expf(fminf(fmaxf(p, -5.0f), 5.0f));
        c = ok ? c : 0.0f;
        acc.x += lof(a.y) * c;
        acc.y += hif(a.y) * c;
        acc.z += lof(a.w) * c;
        acc.w += hif(a.w) * c;
        z += c;
    }
#undef GLOAD

    acc.x += __shfl_xor(acc.x, 32);
    acc.y += __shfl_xor(acc.y, 32);
    acc.z += __shfl_xor(acc.z, 32);
    acc.w += __shfl_xor(acc.w, 32);
    z     += __shfl_xor(z, 32);

    if (half == 0) {
        float inv = 1.0f / (z + 1e-6f);
        ((float4*)(out + (long long)node * HID))[m] =
            make_float4(acc.x * inv, acc.y * inv, acc.z * inv, acc.w * inv);
    }
}

// ================= fallback path (ws too small / N too large) =================

__global__ void count_kernel(const int* __restrict__ ei, int* __restrict__ counts,
                             int* __restrict__ pos, int E) {
    int e = blockIdx.x * blockDim.x + threadIdx.x;
    if (e < E) pos[e] = atomicAdd(&counts[ei[E + e]], 1);
}

__global__ void fill_kernel(const int* __restrict__ ei, const int* __restrict__ offsets,
                            const int* __restrict__ pos, int* __restrict__ srcs, int E) {
    int e = blockIdx.x * blockDim.x + threadIdx.x;
    if (e < E) srcs[offsets[ei[E + e]] + pos[e]] = ei[e];
}

__global__ __launch_bounds__(256) void reduce_f32(
        const float* __restrict__ q, const float* __restrict__ k,
        const float* __restrict__ v, const int* __restrict__ offsets,
        const int* __restrict__ srcs, float* __restrict__ out, int N) {
    int node = blockIdx.x * 4 + (threadIdx.x >> 6);
    if (node >= N) return;
    int l = threadIdx.x & 63;
    float2 qv = ((const float2*)(q + (long long)node * HID))[l];
    float accx = 0.0f, accy = 0.0f, z = 0.0f;
    int beg = offsets[node], end = offsets[node + 1];
    for (int i = beg; i < end; i++) {
        int s = srcs[i];
        float2 kk = ((const float2*)(k + (long long)s * HID))[l];
        float2 vv = ((const float2*)(v + (long long)s * HID))[l];
        float p = (kk.x * qv.x + kk.y * qv.y) * 0.25f;
        p += __shfl_xor(p, 1);
        p += __shfl_xor(p, 2);
        p += __shfl_xor(p, 4);
        float c = __expf(fminf(fmaxf(p, -5.0f), 5.0f));
        accx += vv.x * c; accy += vv.y * c; z += c;
    }
    float inv = 1.0f / (z + 1e-6f);
    ((float2*)(out + (long long)node * HID))[l] = make_float2(accx * inv, accy * inv);
}

// scan helpers for fallback (kept from R8)
__global__ void scanA_kernel(const u32* __restrict__ counts, int* __restrict__ offsets,
                             int* __restrict__ partials, int M) {
    __shared__ int sdata[256];
    int tid = threadIdx.x;
    int base = blockIdx.x * 2048 + tid * 8;
    int v[8];
    int tsum = 0;
    for (int j = 0; j < 8; j++) {
        int idx = base + j;
        v[j] = (idx < M) ? (int)counts[idx] : 0;
        tsum += v[j];
    }
    sdata[tid] = tsum;
    __syncthreads();
    for (int off = 1; off < 256; off <<= 1) {
        int x = sdata[tid];
        int y = (tid >= off) ? sdata[tid - off] : 0;
        __syncthreads();
        sdata[tid] = x + y;
        __syncthreads();
    }
    int excl = sdata[tid] - tsum;
    for (int j = 0; j < 8; j++) {
        int idx = base + j;
        if (idx < M) offsets[idx] = excl;
        excl += v[j];
    }
    if (tid == 255) partials[blockIdx.x] = sdata[255];
}

__global__ void scanC_kernel(int* __restrict__ offsets, const int* __restrict__ partials,
                             int M, int E, int nbA) {
    __shared__ int sp[256];
    int tid = threadIdx.x;
    if (tid == 0) {
        int run = 0;
        for (int i = 0; i < nbA; i++) { sp[i] = run; run += partials[i]; }
    }
    __syncthreads();
    int idx = blockIdx.x * blockDim.x + tid;
    if (idx < M) offsets[idx] += sp[idx >> 11];
    if (idx == 0) offsets[M] = E;
}

extern "C" void kernel_launch(void* const* d_in, const int* in_sizes, int n_in,
                              void* d_out, int out_size, void* d_ws, size_t ws_size,
                              hipStream_t stream) {
    const float* q = (const float*)d_in[0];
    const float* k = (const float*)d_in[1];
    const float* v = (const float*)d_in[2];
    const int* ei = (const int*)d_in[3];
    float* out = (float*)d_out;

    int E = in_sizes[3] / 2;      // 800000
    int N = in_sizes[0] / HID;    // 50000

    int eblocks = (E + 255) / 256;
    int nbA = (N + 2047) / 2048;
    int nblocksN = (N + 255) / 256;

    int W = (N + 1) / 2;                          // packed-pair words
    int NB = (E + CHUNK - 1) >> CSHIFT;           // chunks

    size_t kv_bytes = (size_t)N * 256 * sizeof(u16);
    size_t need = kv_bytes + ((size_t)NB * W + N + N + 1 + 256) * 4
                + 2 * ((size_t)E + 8) * 2 + 64;

    bool primary = (W <= MAXW) && (N <= 1024 * ((N + 1023) / 1024)) && (ws_size >= need);

    if (primary) {
        u16* kv = (u16*)d_ws;
        u32* Hp = (u32*)((char*)d_ws + kv_bytes);
        u32* t = Hp + (size_t)NB * W;
        int* offsets = (int*)(t + N);
        int* partials = offsets + N + 1;          // unused in primary; keeps layout
        u16* lrank = (u16*)(partials + 256);
        u16* srcs = lrank + ((E + 8) & ~1);

        int packBlocks = (N * 64 + 255) / 256;

        hist_kernel<<<NB, 1024, 0, stream>>>(ei, Hp, lrank, E, W);
        scan_node_kernel<<<(W + 255) / 256, 256, 0, stream>>>(Hp, t, W, NB, N);
        scanOne_kernel<<<1, 1024, 0, stream>>>(t, offsets, N, E);
        packscatter_kernel<<<packBlocks + eblocks, 256, 0, stream>>>(
            k, v, kv, ei, Hp, lrank, offsets, srcs, N, E, W, packBlocks);
        int rgrid = (N + 1) / 2;
        reduce_packed<<<rgrid, 128, 0, stream>>>(q, kv, offsets, srcs, out, N);
    } else {
        int* counts = (int*)d_ws;
        int* offsets = counts + N;
        int* partials = offsets + N + 1;
        int* pos = partials + 256;
        int* srcs = pos + E;

        hipMemsetAsync(counts, 0, (size_t)N * sizeof(int), stream);
        count_kernel<<<eblocks, 256, 0, stream>>>(ei, counts, pos, E);
        scanA_kernel<<<nbA, 256, 0, stream>>>((const u32*)counts, offsets, partials, N);
        scanC_kernel<<<nblocksN, 256, 0, stream>>>(offsets, partials, N, E, nbA);
        fill_kernel<<<eblocks, 256, 0, stream>>>(ei, offsets, pos, srcs, E);
        int rgrid = (N + 3) / 4;
        reduce_f32<<<rgrid, 256, 0, stream>>>(q, k, v, offsets, srcs, out, N);
    }
}

// Round 10
// 121.180 us; speedup vs baseline: 1.5448x; 1.5448x over previous
//
#include <hip/hip_runtime.h>

#define HID 128
#define CHUNK 16384      // edges per histogram chunk (power of 2)
#define CSHIFT 14
#define MAXW 25088       // LDS packed-pair words (supports N <= 50176), 100 KB

typedef unsigned short u16;
typedef unsigned int u32;

__device__ __forceinline__ float bf2f(u16 u) { return __uint_as_float(((u32)u) << 16); }
__device__ __forceinline__ float lof(u32 w) { return __uint_as_float(w << 16); }
__device__ __forceinline__ float hif(u32 w) { return __uint_as_float(w & 0xFFFF0000u); }
__device__ __forceinline__ u16 f2bf(float f) {
    u32 x = __float_as_uint(f);
    return (u16)((x + 0x7FFF + ((x >> 16) & 1)) >> 16);  // RNE
}

// ---- per-chunk LDS histogram over ALL nodes (packed u16 pairs) + local edge rank ----
__global__ __launch_bounds__(1024) void hist_kernel(const int* __restrict__ ei,
        u32* __restrict__ Hp, u16* __restrict__ lrank, int E, int W) {
    __shared__ u32 hcnt[MAXW];
    int c = blockIdx.x;
    for (int j = threadIdx.x; j < W; j += 1024) hcnt[j] = 0;
    __syncthreads();
    int beg = c << CSHIFT;
    int end = min(E, beg + CHUNK);
    for (int i = beg + (int)threadIdx.x; i < end; i += 1024) {
        int d = ei[E + i];
        u32 sh = (u32)(d & 1) << 4;               // 0 or 16
        u32 old = atomicAdd(&hcnt[d >> 1], 1u << sh);
        lrank[i] = (u16)((old >> sh) & 0xFFFFu);  // low half can't carry: count<=16384
    }
    __syncthreads();
    for (int j = threadIdx.x; j < W; j += 1024) Hp[(size_t)c * W + j] = hcnt[j];
}

// ---- convert Hp to exclusive cumulative-over-chunks (in place), emit node totals t ----
__global__ void scan_node_kernel(u32* __restrict__ Hp, u32* __restrict__ t,
                                 int W, int NB, int N) {
    int j = blockIdx.x * blockDim.x + threadIdx.x;
    if (j >= W) return;
    u32 lo = 0, hi = 0;
    for (int c = 0; c < NB; c++) {
        size_t idx = (size_t)c * W + j;
        u32 w = Hp[idx];
        Hp[idx] = lo | (hi << 16);     // bases fit u16 (deg <= 65535)
        lo += w & 0xFFFFu;
        hi += w >> 16;
    }
    int n0 = 2 * j, n1 = 2 * j + 1;
    if (n0 < N) t[n0] = lo;
    if (n1 < N) t[n1] = hi;
}

// ---- scan phase A: multi-block local scan + block totals (R2 lesson: NEVER single-block) ----
__global__ void scanA_kernel(const u32* __restrict__ counts, int* __restrict__ offsets,
                             int* __restrict__ partials, int M) {
    __shared__ int sdata[256];
    int tid = threadIdx.x;
    int base = blockIdx.x * 2048 + tid * 8;
    int v[8];
    int tsum = 0;
    for (int j = 0; j < 8; j++) {
        int idx = base + j;
        v[j] = (idx < M) ? (int)counts[idx] : 0;
        tsum += v[j];
    }
    sdata[tid] = tsum;
    __syncthreads();
    for (int off = 1; off < 256; off <<= 1) {
        int x = sdata[tid];
        int y = (tid >= off) ? sdata[tid - off] : 0;
        __syncthreads();
        sdata[tid] = x + y;
        __syncthreads();
    }
    int excl = sdata[tid] - tsum;
    for (int j = 0; j < 8; j++) {
        int idx = base + j;
        if (idx < M) offsets[idx] = excl;
        excl += v[j];
    }
    if (tid == 255) partials[blockIdx.x] = sdata[255];
}

// ---- scan phase C (B fused): add block bases ----
__global__ void scanC_kernel(int* __restrict__ offsets, const int* __restrict__ partials,
                             int M, int E, int nbA) {
    __shared__ int sp[256];
    int tid = threadIdx.x;
    if (tid == 0) {
        int run = 0;
        for (int i = 0; i < nbA; i++) { sp[i] = run; run += partials[i]; }
    }
    __syncthreads();
    int idx = blockIdx.x * blockDim.x + tid;
    if (idx < M) offsets[idx] += sp[idx >> 11];
    if (idx == 0) offsets[M] = E;
}

// ---- fused pack (k*0.25,v -> bf16 rows) + scatter (atomic-free), range-split ----
__global__ void packscatter_kernel(const float* __restrict__ k, const float* __restrict__ v,
                                   u16* __restrict__ kv, const int* __restrict__ ei,
                                   const u32* __restrict__ Hp, const u16* __restrict__ lrank,
                                   const int* __restrict__ offsets, u16* __restrict__ srcs,
                                   int N, int E, int W, int packBlocks) {
    if ((int)blockIdx.x < packBlocks) {
        int g = blockIdx.x * 256 + threadIdx.x;   // node*64 + lane
        int node = g >> 6, l = g & 63;
        if (node >= N) return;
        float2 kk = ((const float2*)(k + (long long)node * HID))[l];
        float2 vv = ((const float2*)(v + (long long)node * HID))[l];
        ushort4 o;
        o.x = f2bf(kk.x * 0.25f);   // fold 1/SCALE (exact pow2) into k
        o.y = f2bf(kk.y * 0.25f);
        o.z = f2bf(vv.x);
        o.w = f2bf(vv.y);
        ((ushort4*)(kv + (long long)node * 256))[l] = o;
    } else {
        int e = (blockIdx.x - packBlocks) * 256 + threadIdx.x;
        if (e >= E) return;
        int c = e >> CSHIFT;
        int d = ei[E + e];
        u32 sh = (u32)(d & 1) << 4;
        u32 b = (Hp[(size_t)c * W + (d >> 1)] >> sh) & 0xFFFFu;
        int pos = offsets[d] + (int)b + (int)lrank[e];
        srcs[pos] = (u16)ei[e];
    }
}

// ---- per-node reduction: 4 dims/lane, 2 edges/wave-step, 2 nodes/block ----
__global__ __launch_bounds__(128) void reduce_packed(
        const float* __restrict__ q, const u16* __restrict__ kv,
        const int* __restrict__ offsets, const u16* __restrict__ srcs,
        float* __restrict__ out, int N) {
    int node = blockIdx.x * 2 + (threadIdx.x >> 6);
    if (node >= N) return;
    int l = threadIdx.x & 63;
    int m = l & 31;          // 4-dim group within the row
    int half = l >> 5;       // which edge of the pair this lane handles

    float4 qv = ((const float4*)(q + (long long)node * HID))[m];
    const char* kvb = (const char*)kv;
    u32 laneoff = (u32)m << 4;   // 16B per group
    float4 acc = make_float4(0.0f, 0.0f, 0.0f, 0.0f);
    float z = 0.0f;

    int beg = offsets[node];
    int end = offsets[node + 1];
    int i = beg;

#define GLOAD(s_) (*(const uint4*)(kvb + (((u32)(s_) << 9) + laneoff)))

    for (; i + 8 <= end; i += 8) {
        u32 sA0 = srcs[i + 0], sB0 = srcs[i + 1];
        u32 sA1 = srcs[i + 2], sB1 = srcs[i + 3];
        u32 sA2 = srcs[i + 4], sB2 = srcs[i + 5];
        u32 sA3 = srcs[i + 6], sB3 = srcs[i + 7];
        uint4 a0 = GLOAD(half ? sB0 : sA0);
        uint4 a1 = GLOAD(half ? sB1 : sA1);
        uint4 a2 = GLOAD(half ? sB2 : sA2);
        uint4 a3 = GLOAD(half ? sB3 : sA3);

        float p0 = lof(a0.x) * qv.x + hif(a0.x) * qv.y + lof(a0.z) * qv.z + hif(a0.z) * qv.w;
        float p1 = lof(a1.x) * qv.x + hif(a1.x) * qv.y + lof(a1.z) * qv.z + hif(a1.z) * qv.w;
        float p2 = lof(a2.x) * qv.x + hif(a2.x) * qv.y + lof(a2.z) * qv.z + hif(a2.z) * qv.w;
        float p3 = lof(a3.x) * qv.x + hif(a3.x) * qv.y + lof(a3.z) * qv.z + hif(a3.z) * qv.w;

        p0 += __shfl_xor(p0, 1); p1 += __shfl_xor(p1, 1);
        p2 += __shfl_xor(p2, 1); p3 += __shfl_xor(p3, 1);
        p0 += __shfl_xor(p0, 2); p1 += __shfl_xor(p1, 2);
        p2 += __shfl_xor(p2, 2); p3 += __shfl_xor(p3, 2);

        float c0 = __expf(fminf(fmaxf(p0, -5.0f), 5.0f));
        float c1 = __expf(fminf(fmaxf(p1, -5.0f), 5.0f));
        float c2 = __expf(fminf(fmaxf(p2, -5.0f), 5.0f));
        float c3 = __expf(fminf(fmaxf(p3, -5.0f), 5.0f));

        acc.x += lof(a0.y) * c0 + lof(a1.y) * c1 + lof(a2.y) * c2 + lof(a3.y) * c3;
        acc.y += hif(a0.y) * c0 + hif(a1.y) * c1 + hif(a2.y) * c2 + hif(a3.y) * c3;
        acc.z += lof(a0.w) * c0 + lof(a1.w) * c1 + lof(a2.w) * c2 + lof(a3.w) * c3;
        acc.w += hif(a0.w) * c0 + hif(a1.w) * c1 + hif(a2.w) * c2 + hif(a3.w) * c3;
        z += c0 + c1 + c2 + c3;
    }
    for (; i < end; i += 2) {
        int idx = i + half;
        bool ok = idx < end;
        u32 s = srcs[ok ? idx : i];
        uint4 a = GLOAD(s);
        float p = lof(a.x) * qv.x + hif(a.x) * qv.y + lof(a.z) * qv.z + hif(a.z) * qv.w;
        p += __shfl_xor(p, 1);
        p += __shfl_xor(p, 2);
        float c = __expf(fminf(fmaxf(p, -5.0f), 5.0f));
        c = ok ? c : 0.0f;
        acc.x += lof(a.y) * c;
        acc.y += hif(a.y) * c;
        acc.z += lof(a.w) * c;
        acc.w += hif(a.w) * c;
        z += c;
    }
#undef GLOAD

    acc.x += __shfl_xor(acc.x, 32);
    acc.y += __shfl_xor(acc.y, 32);
    acc.z += __shfl_xor(acc.z, 32);
    acc.w += __shfl_xor(acc.w, 32);
    z     += __shfl_xor(z, 32);

    if (half == 0) {
        float inv = 1.0f / (z + 1e-6f);
        ((float4*)(out + (long long)node * HID))[m] =
            make_float4(acc.x * inv, acc.y * inv, acc.z * inv, acc.w * inv);
    }
}

// ================= fallback path (ws too small / N too large) =================

__global__ void count_kernel(const int* __restrict__ ei, int* __restrict__ counts,
                             int* __restrict__ pos, int E) {
    int e = blockIdx.x * blockDim.x + threadIdx.x;
    if (e < E) pos[e] = atomicAdd(&counts[ei[E + e]], 1);
}

__global__ void fill_kernel(const int* __restrict__ ei, const int* __restrict__ offsets,
                            const int* __restrict__ pos, int* __restrict__ srcs, int E) {
    int e = blockIdx.x * blockDim.x + threadIdx.x;
    if (e < E) srcs[offsets[ei[E + e]] + pos[e]] = ei[e];
}

__global__ __launch_bounds__(256) void reduce_f32(
        const float* __restrict__ q, const float* __restrict__ k,
        const float* __restrict__ v, const int* __restrict__ offsets,
        const int* __restrict__ srcs, float* __restrict__ out, int N) {
    int node = blockIdx.x * 4 + (threadIdx.x >> 6);
    if (node >= N) return;
    int l = threadIdx.x & 63;
    float2 qv = ((const float2*)(q + (long long)node * HID))[l];
    float accx = 0.0f, accy = 0.0f, z = 0.0f;
    int beg = offsets[node], end = offsets[node + 1];
    for (int i = beg; i < end; i++) {
        int s = srcs[i];
        float2 kk = ((const float2*)(k + (long long)s * HID))[l];
        float2 vv = ((const float2*)(v + (long long)s * HID))[l];
        float p = (kk.x * qv.x + kk.y * qv.y) * 0.25f;
        p += __shfl_xor(p, 1);
        p += __shfl_xor(p, 2);
        p += __shfl_xor(p, 4);
        float c = __expf(fminf(fmaxf(p, -5.0f), 5.0f));
        accx += vv.x * c; accy += vv.y * c; z += c;
    }
    float inv = 1.0f / (z + 1e-6f);
    ((float2*)(out + (long long)node * HID))[l] = make_float2(accx * inv, accy * inv);
}

extern "C" void kernel_launch(void* const* d_in, const int* in_sizes, int n_in,
                              void* d_out, int out_size, void* d_ws, size_t ws_size,
                              hipStream_t stream) {
    const float* q = (const float*)d_in[0];
    const float* k = (const float*)d_in[1];
    const float* v = (const float*)d_in[2];
    const int* ei = (const int*)d_in[3];
    float* out = (float*)d_out;

    int E = in_sizes[3] / 2;      // 800000
    int N = in_sizes[0] / HID;    // 50000

    int eblocks = (E + 255) / 256;
    int nbA = (N + 2047) / 2048;                  // 25 (<=256 cap)
    int nblocksN = (N + 255) / 256;

    int W = (N + 1) / 2;                          // packed-pair words
    int NB = (E + CHUNK - 1) >> CSHIFT;           // chunks

    size_t kv_bytes = (size_t)N * 256 * sizeof(u16);
    size_t need = kv_bytes + ((size_t)NB * W + N + N + 1 + 256) * 4
                + 2 * ((size_t)E + 8) * 2 + 64;

    bool primary = (W <= MAXW) && (nbA <= 256) && (ws_size >= need);

    if (primary) {
        u16* kv = (u16*)d_ws;
        u32* Hp = (u32*)((char*)d_ws + kv_bytes);
        u32* t = Hp + (size_t)NB * W;
        int* offsets = (int*)(t + N);
        int* partials = offsets + N + 1;
        u16* lrank = (u16*)(partials + 256);
        u16* srcs = lrank + ((E + 8) & ~1);

        int packBlocks = (N * 64 + 255) / 256;

        hist_kernel<<<NB, 1024, 0, stream>>>(ei, Hp, lrank, E, W);
        scan_node_kernel<<<(W + 255) / 256, 256, 0, stream>>>(Hp, t, W, NB, N);
        scanA_kernel<<<nbA, 256, 0, stream>>>(t, offsets, partials, N);
        scanC_kernel<<<nblocksN, 256, 0, stream>>>(offsets, partials, N, E, nbA);
        packscatter_kernel<<<packBlocks + eblocks, 256, 0, stream>>>(
            k, v, kv, ei, Hp, lrank, offsets, srcs, N, E, W, packBlocks);
        int rgrid = (N + 1) / 2;
        reduce_packed<<<rgrid, 128, 0, stream>>>(q, kv, offsets, srcs, out, N);
    } else {
        int* counts = (int*)d_ws;
        int* offsets = counts + N;
        int* partials = offsets + N + 1;
        int* pos = partials + 256;
        int* srcs = pos + E;

        hipMemsetAsync(counts, 0, (size_t)N * sizeof(int), stream);
        count_kernel<<<eblocks, 256, 0, stream>>>(ei, counts, pos, E);
        scanA_kernel<<<nbA, 256, 0, stream>>>((const u32*)counts, offsets, partials, N);
        scanC_kernel<<<nblocksN, 256, 0, stream>>>(offsets, partials, N, E, nbA);
        fill_kernel<<<eblocks, 256, 0, stream>>>(ei, offsets, pos, srcs, E);
        int rgrid = (N + 3) / 4;
        reduce_f32<<<rgrid, 256, 0, stream>>>(q, k, v, offsets, srcs, out, N);
    }
}

// Round 11
// 111.163 us; speedup vs baseline: 1.6840x; 1.0901x over previous
//
#include <hip/hip_runtime.h>

#define HID 128
#define CHUNK 16384      // edges per histogram chunk (power of 2)
#define CSHIFT 14
#define MAXW 25088       // LDS packed-pair words (supports N <= 50176), 100 KB

typedef unsigned short u16;
typedef unsigned int u32;

__device__ __forceinline__ float lof(u32 w) { return __uint_as_float(w << 16); }
__device__ __forceinline__ float hif(u32 w) { return __uint_as_float(w & 0xFFFF0000u); }
__device__ __forceinline__ u16 f2bf(float f) {
    u32 x = __float_as_uint(f);
    return (u16)((x + 0x7FFF + ((x >> 16) & 1)) >> 16);  // RNE
}

// ---- per-chunk LDS histogram over ALL nodes (packed u16 pairs) + local edge rank ----
__global__ __launch_bounds__(1024) void hist_kernel(const int* __restrict__ ei,
        u32* __restrict__ Hp, u16* __restrict__ lrank, int E, int W) {
    __shared__ u32 hcnt[MAXW];
    int c = blockIdx.x;
    for (int j = threadIdx.x; j < W; j += 1024) hcnt[j] = 0;
    __syncthreads();
    int beg = c << CSHIFT;
    int end = min(E, beg + CHUNK);
    for (int i = beg + (int)threadIdx.x; i < end; i += 1024) {
        int d = ei[E + i];
        u32 sh = (u32)(d & 1) << 4;               // 0 or 16
        u32 old = atomicAdd(&hcnt[d >> 1], 1u << sh);
        lrank[i] = (u16)((old >> sh) & 0xFFFFu);  // low half can't carry: count<=16384
    }
    __syncthreads();
    for (int j = threadIdx.x; j < W; j += 1024) Hp[(size_t)c * W + j] = hcnt[j];
}

// ---- fused: chunk-prefix over Hp (batched, MLP 8) + block-level node scan ----
// 1024 threads/block; thread j handles W-word j (nodes 2j, 2j+1).
// Each block covers 2048 nodes -> scanC granularity (idx>>11) unchanged.
__global__ __launch_bounds__(1024) void scan_fused_kernel(u32* __restrict__ Hp,
        int* __restrict__ offsets, int* __restrict__ partials, int W, int NB, int N) {
    __shared__ int sdata[1024];
    int tid = threadIdx.x;
    int j = blockIdx.x * 1024 + tid;
    u32 lo = 0, hi = 0;
    if (j < W) {
        int c = 0;
        for (; c + 8 <= NB; c += 8) {
            u32 w[8];
#pragma unroll
            for (int t = 0; t < 8; t++) w[t] = Hp[(size_t)(c + t) * W + j];
#pragma unroll
            for (int t = 0; t < 8; t++) {
                Hp[(size_t)(c + t) * W + j] = lo | (hi << 16);   // bases fit u16 (deg<=65535)
                lo += w[t] & 0xFFFFu;
                hi += w[t] >> 16;
            }
        }
        for (; c < NB; c++) {
            size_t idx = (size_t)c * W + j;
            u32 w = Hp[idx];
            Hp[idx] = lo | (hi << 16);
            lo += w & 0xFFFFu;
            hi += w >> 16;
        }
    }
    int s = (int)(lo + hi);
    sdata[tid] = s;
    __syncthreads();
    for (int off = 1; off < 1024; off <<= 1) {
        int x = sdata[tid];
        int y = (tid >= off) ? sdata[tid - off] : 0;
        __syncthreads();
        sdata[tid] = x + y;
        __syncthreads();
    }
    int excl = sdata[tid] - s;
    if (j < W) {
        int n0 = 2 * j, n1 = 2 * j + 1;
        offsets[n0] = excl;                         // local (block) exclusive; scanC adds base
        if (n1 < N) offsets[n1] = excl + (int)lo;
    }
    if (tid == 1023) partials[blockIdx.x] = sdata[1023];
}

// ---- scan phase C: add block bases (196 blocks; also sets offsets[N]) ----
__global__ void scanC_kernel(int* __restrict__ offsets, const int* __restrict__ partials,
                             int M, int E, int nbA) {
    __shared__ int sp[256];
    int tid = threadIdx.x;
    if (tid == 0) {
        int run = 0;
        for (int i = 0; i < nbA; i++) { sp[i] = run; run += partials[i]; }
    }
    __syncthreads();
    int idx = blockIdx.x * blockDim.x + tid;
    if (idx < M) offsets[idx] += sp[idx >> 11];
    if (idx == 0) offsets[M] = E;
}

// ---- fused pack (k*0.25,v -> bf16 rows) + scatter (atomic-free), range-split ----
__global__ void packscatter_kernel(const float* __restrict__ k, const float* __restrict__ v,
                                   u16* __restrict__ kv, const int* __restrict__ ei,
                                   const u32* __restrict__ Hp, const u16* __restrict__ lrank,
                                   const int* __restrict__ offsets, u16* __restrict__ srcs,
                                   int N, int E, int W, int packBlocks) {
    if ((int)blockIdx.x < packBlocks) {
        int g = blockIdx.x * 256 + threadIdx.x;   // node*64 + lane
        int node = g >> 6, l = g & 63;
        if (node >= N) return;
        float2 kk = ((const float2*)(k + (long long)node * HID))[l];
        float2 vv = ((const float2*)(v + (long long)node * HID))[l];
        ushort4 o;
        o.x = f2bf(kk.x * 0.25f);   // fold 1/SCALE (exact pow2) into k
        o.y = f2bf(kk.y * 0.25f);
        o.z = f2bf(vv.x);
        o.w = f2bf(vv.y);
        ((ushort4*)(kv + (long long)node * 256))[l] = o;
    } else {
        int e = (blockIdx.x - packBlocks) * 256 + threadIdx.x;
        if (e >= E) return;
        int c = e >> CSHIFT;
        int d = ei[E + e];
        u32 sh = (u32)(d & 1) << 4;
        u32 b = (Hp[(size_t)c * W + (d >> 1)] >> sh) & 0xFFFFu;
        int pos = offsets[d] + (int)b + (int)lrank[e];
        srcs[pos] = (u16)ei[e];
    }
}

// ---- per-node reduction: 4 dims/lane, 2 edges/wave-step, 2 nodes/block ----
__global__ __launch_bounds__(128) void reduce_packed(
        const float* __restrict__ q, const u16* __restrict__ kv,
        const int* __restrict__ offsets, const u16* __restrict__ srcs,
        float* __restrict__ out, int N) {
    int node = blockIdx.x * 2 + (threadIdx.x >> 6);
    if (node >= N) return;
    int l = threadIdx.x & 63;
    int m = l & 31;          // 4-dim group within the row
    int half = l >> 5;       // which edge of the pair this lane handles

    float4 qv = ((const float4*)(q + (long long)node * HID))[m];
    const char* kvb = (const char*)kv;
    u32 laneoff = (u32)m << 4;   // 16B per group
    float4 acc = make_float4(0.0f, 0.0f, 0.0f, 0.0f);
    float z = 0.0f;

    int beg = offsets[node];
    int end = offsets[node + 1];
    int i = beg;

#define GLOAD(s_) (*(const uint4*)(kvb + (((u32)(s_) << 9) + laneoff)))

    for (; i + 8 <= end; i += 8) {
        u32 sA0 = srcs[i + 0], sB0 = srcs[i + 1];
        u32 sA1 = srcs[i + 2], sB1 = srcs[i + 3];
        u32 sA2 = srcs[i + 4], sB2 = srcs[i + 5];
        u32 sA3 = srcs[i + 6], sB3 = srcs[i + 7];
        uint4 a0 = GLOAD(half ? sB0 : sA0);
        uint4 a1 = GLOAD(half ? sB1 : sA1);
        uint4 a2 = GLOAD(half ? sB2 : sA2);
        uint4 a3 = GLOAD(half ? sB3 : sA3);

        float p0 = lof(a0.x) * qv.x + hif(a0.x) * qv.y + lof(a0.z) * qv.z + hif(a0.z) * qv.w;
        float p1 = lof(a1.x) * qv.x + hif(a1.x) * qv.y + lof(a1.z) * qv.z + hif(a1.z) * qv.w;
        float p2 = lof(a2.x) * qv.x + hif(a2.x) * qv.y + lof(a2.z) * qv.z + hif(a2.z) * qv.w;
        float p3 = lof(a3.x) * qv.x + hif(a3.x) * qv.y + lof(a3.z) * qv.z + hif(a3.z) * qv.w;

        p0 += __shfl_xor(p0, 1); p1 += __shfl_xor(p1, 1);
        p2 += __shfl_xor(p2, 1); p3 += __shfl_xor(p3, 1);
        p0 += __shfl_xor(p0, 2); p1 += __shfl_xor(p1, 2);
        p2 += __shfl_xor(p2, 2); p3 += __shfl_xor(p3, 2);

        float c0 = __expf(fminf(fmaxf(p0, -5.0f), 5.0f));
        float c1 = __expf(fminf(fmaxf(p1, -5.0f), 5.0f));
        float c2 = __expf(fminf(fmaxf(p2, -5.0f), 5.0f));
        float c3 = __expf(fminf(fmaxf(p3, -5.0f), 5.0f));

        acc.x += lof(a0.y) * c0 + lof(a1.y) * c1 + lof(a2.y) * c2 + lof(a3.y) * c3;
        acc.y += hif(a0.y) * c0 + hif(a1.y) * c1 + hif(a2.y) * c2 + hif(a3.y) * c3;
        acc.z += lof(a0.w) * c0 + lof(a1.w) * c1 + lof(a2.w) * c2 + lof(a3.w) * c3;
        acc.w += hif(a0.w) * c0 + hif(a1.w) * c1 + hif(a2.w) * c2 + hif(a3.w) * c3;
        z += c0 + c1 + c2 + c3;
    }
    for (; i < end; i += 2) {
        int idx = i + half;
        bool ok = idx < end;
        u32 s = srcs[ok ? idx : i];
        uint4 a = GLOAD(s);
        float p = lof(a.x) * qv.x + hif(a.x) * qv.y + lof(a.z) * qv.z + hif(a.z) * qv.w;
        p += __shfl_xor(p, 1);
        p += __shfl_xor(p, 2);
        float c = __expf(fminf(fmaxf(p, -5.0f), 5.0f));
        c = ok ? c : 0.0f;
        acc.x += lof(a.y) * c;
        acc.y += hif(a.y) * c;
        acc.z += lof(a.w) * c;
        acc.w += hif(a.w) * c;
        z += c;
    }
#undef GLOAD

    acc.x += __shfl_xor(acc.x, 32);
    acc.y += __shfl_xor(acc.y, 32);
    acc.z += __shfl_xor(acc.z, 32);
    acc.w += __shfl_xor(acc.w, 32);
    z     += __shfl_xor(z, 32);

    if (half == 0) {
        float inv = 1.0f / (z + 1e-6f);
        ((float4*)(out + (long long)node * HID))[m] =
            make_float4(acc.x * inv, acc.y * inv, acc.z * inv, acc.w * inv);
    }
}

// ================= fallback path (ws too small / N too large) =================

__global__ void count_kernel(const int* __restrict__ ei, int* __restrict__ counts,
                             int* __restrict__ pos, int E) {
    int e = blockIdx.x * blockDim.x + threadIdx.x;
    if (e < E) pos[e] = atomicAdd(&counts[ei[E + e]], 1);
}

__global__ void fill_kernel(const int* __restrict__ ei, const int* __restrict__ offsets,
                            const int* __restrict__ pos, int* __restrict__ srcs, int E) {
    int e = blockIdx.x * blockDim.x + threadIdx.x;
    if (e < E) srcs[offsets[ei[E + e]] + pos[e]] = ei[e];
}

__global__ __launch_bounds__(256) void reduce_f32(
        const float* __restrict__ q, const float* __restrict__ k,
        const float* __restrict__ v, const int* __restrict__ offsets,
        const int* __restrict__ srcs, float* __restrict__ out, int N) {
    int node = blockIdx.x * 4 + (threadIdx.x >> 6);
    if (node >= N) return;
    int l = threadIdx.x & 63;
    float2 qv = ((const float2*)(q + (long long)node * HID))[l];
    float accx = 0.0f, accy = 0.0f, z = 0.0f;
    int beg = offsets[node], end = offsets[node + 1];
    for (int i = beg; i < end; i++) {
        int s = srcs[i];
        float2 kk = ((const float2*)(k + (long long)s * HID))[l];
        float2 vv = ((const float2*)(v + (long long)s * HID))[l];
        float p = (kk.x * qv.x + kk.y * qv.y) * 0.25f;
        p += __shfl_xor(p, 1);
        p += __shfl_xor(p, 2);
        p += __shfl_xor(p, 4);
        float c = __expf(fminf(fmaxf(p, -5.0f), 5.0f));
        accx += vv.x * c; accy += vv.y * c; z += c;
    }
    float inv = 1.0f / (z + 1e-6f);
    ((float2*)(out + (long long)node * HID))[l] = make_float2(accx * inv, accy * inv);
}

// multi-block scan for fallback (R2 lesson: NEVER single-block over 50K)
__global__ void scanA_kernel(const u32* __restrict__ counts, int* __restrict__ offsets,
                             int* __restrict__ partials, int M) {
    __shared__ int sdata[256];
    int tid = threadIdx.x;
    int base = blockIdx.x * 2048 + tid * 8;
    int v[8];
    int tsum = 0;
    for (int j = 0; j < 8; j++) {
        int idx = base + j;
        v[j] = (idx < M) ? (int)counts[idx] : 0;
        tsum += v[j];
    }
    sdata[tid] = tsum;
    __syncthreads();
    for (int off = 1; off < 256; off <<= 1) {
        int x = sdata[tid];
        int y = (tid >= off) ? sdata[tid - off] : 0;
        __syncthreads();
        sdata[tid] = x + y;
        __syncthreads();
    }
    int excl = sdata[tid] - tsum;
    for (int j = 0; j < 8; j++) {
        int idx = base + j;
        if (idx < M) offsets[idx] = excl;
        excl += v[j];
    }
    if (tid == 255) partials[blockIdx.x] = sdata[255];
}

extern "C" void kernel_launch(void* const* d_in, const int* in_sizes, int n_in,
                              void* d_out, int out_size, void* d_ws, size_t ws_size,
                              hipStream_t stream) {
    const float* q = (const float*)d_in[0];
    const float* k = (const float*)d_in[1];
    const float* v = (const float*)d_in[2];
    const int* ei = (const int*)d_in[3];
    float* out = (float*)d_out;

    int E = in_sizes[3] / 2;      // 800000
    int N = in_sizes[0] / HID;    // 50000

    int eblocks = (E + 255) / 256;
    int nbA = (N + 2047) / 2048;                  // 25 (<=256 cap)
    int nblocksN = (N + 255) / 256;

    int W = (N + 1) / 2;                          // packed-pair words
    int NB = (E + CHUNK - 1) >> CSHIFT;           // chunks (49)
    int nbF = (W + 1023) / 1024;                  // fused-scan blocks (25, covers 2048 nodes each)

    size_t kv_bytes = (size_t)N * 256 * sizeof(u16);
    size_t need = kv_bytes + ((size_t)NB * W + N + 1 + 256) * 4
                + 2 * ((size_t)E + 8) * 2 + 64;

    bool primary = (W <= MAXW) && (nbF <= 256) && (ws_size >= need);

    if (primary) {
        u16* kv = (u16*)d_ws;
        u32* Hp = (u32*)((char*)d_ws + kv_bytes);
        int* offsets = (int*)(Hp + (size_t)NB * W);
        int* partials = offsets + N + 1;
        u16* lrank = (u16*)(partials + 256);
        u16* srcs = lrank + ((E + 8) & ~1);

        int packBlocks = (N * 64 + 255) / 256;

        hist_kernel<<<NB, 1024, 0, stream>>>(ei, Hp, lrank, E, W);
        scan_fused_kernel<<<nbF, 1024, 0, stream>>>(Hp, offsets, partials, W, NB, N);
        scanC_kernel<<<nblocksN, 256, 0, stream>>>(offsets, partials, N, E, nbF);
        packscatter_kernel<<<packBlocks + eblocks, 256, 0, stream>>>(
            k, v, kv, ei, Hp, lrank, offsets, srcs, N, E, W, packBlocks);
        int rgrid = (N + 1) / 2;
        reduce_packed<<<rgrid, 128, 0, stream>>>(q, kv, offsets, srcs, out, N);
    } else {
        int* counts = (int*)d_ws;
        int* offsets = counts + N;
        int* partials = offsets + N + 1;
        int* pos = partials + 256;
        int* srcs = pos + E;

        hipMemsetAsync(counts, 0, (size_t)N * sizeof(int), stream);
        count_kernel<<<eblocks, 256, 0, stream>>>(ei, counts, pos, E);
        scanA_kernel<<<nbA, 256, 0, stream>>>((const u32*)counts, offsets, partials, N);
        scanC_kernel<<<nblocksN, 256, 0, stream>>>(offsets, partials, N, E, nbA);
        fill_kernel<<<eblocks, 256, 0, stream>>>(ei, offsets, pos, srcs, E);
        int rgrid = (N + 3) / 4;
        reduce_f32<<<rgrid, 256, 0, stream>>>(q, k, v, offsets, srcs, out, N);
    }
}

// Round 12
// 104.808 us; speedup vs baseline: 1.7861x; 1.0606x over previous
//
#include <hip/hip_runtime.h>

#define HID 128
#define CHUNK 16384      // edges per histogram chunk (power of 2)
#define CSHIFT 14
#define MAXW 25088       // max packed-pair words (N <= 50176)
#define WH 12544         // LDS words per hist block (node-half split), 50.2 KB

typedef unsigned short u16;
typedef unsigned int u32;

__device__ __forceinline__ float lof(u32 w) { return __uint_as_float(w << 16); }
__device__ __forceinline__ float hif(u32 w) { return __uint_as_float(w & 0xFFFF0000u); }
__device__ __forceinline__ u16 f2bf(float f) {
    u32 x = __float_as_uint(f);
    return (u16)((x + 0x7FFF + ((x >> 16) & 1)) >> 16);  // RNE
}

// ---- fused: per-(chunk, node-half) LDS histogram + rank  ||  pack k,v->bf16 rows ----
// hist blocks: 2 per chunk, each owns half the node range (50KB LDS, 2-3 blocks/CU).
// pack blocks ride the same launch and fill otherwise-idle CUs (streaming, no deps).
__global__ __launch_bounds__(1024) void histpack_kernel(
        const int* __restrict__ ei, u32* __restrict__ Hp, u16* __restrict__ lrank,
        const float* __restrict__ kin, const float* __restrict__ vin, u16* __restrict__ kv,
        int E, int W, int N, int histBlocks) {
    __shared__ u32 hcnt[WH];
    if ((int)blockIdx.x < histBlocks) {
        int c = blockIdx.x >> 1;          // chunk
        int h = blockIdx.x & 1;           // node-half
        int Wh = (W + 1) >> 1;
        int base = h * Wh;
        int wlen = min(Wh, W - base);
        for (int j = threadIdx.x; j < wlen; j += 1024) hcnt[j] = 0;
        __syncthreads();
        int beg = c << CSHIFT;
        int end = min(E, beg + CHUNK);
        for (int i = beg + (int)threadIdx.x; i < end; i += 1024) {
            int d = ei[E + i];
            int w = d >> 1;
            if (w >= base && w < base + wlen) {
                u32 sh = (u32)(d & 1) << 4;               // 0 or 16
                u32 old = atomicAdd(&hcnt[w - base], 1u << sh);
                lrank[i] = (u16)((old >> sh) & 0xFFFFu);  // count<=16384: no carry
            }
        }
        __syncthreads();
        for (int j = threadIdx.x; j < wlen; j += 1024)
            Hp[(size_t)c * W + base + j] = hcnt[j];
    } else {
        int g = ((int)blockIdx.x - histBlocks) * 1024 + (int)threadIdx.x;  // node*64+lane
        int node = g >> 6, l = g & 63;
        if (node >= N) return;
        float2 kk = ((const float2*)(kin + (long long)node * HID))[l];
        float2 vv = ((const float2*)(vin + (long long)node * HID))[l];
        ushort4 o;
        o.x = f2bf(kk.x * 0.25f);   // fold 1/SCALE (exact pow2) into k
        o.y = f2bf(kk.y * 0.25f);
        o.z = f2bf(vv.x);
        o.w = f2bf(vv.y);
        ((ushort4*)(kv + (long long)node * 256))[l] = o;
    }
}

// ---- fused: chunk-prefix over Hp (batched, MLP 8) + block-level node scan ----
// 1024 threads/block; thread j handles W-word j (nodes 2j, 2j+1); 2048 nodes/block.
__global__ __launch_bounds__(1024) void scan_fused_kernel(u32* __restrict__ Hp,
        int* __restrict__ offsets, int* __restrict__ partials, int W, int NB, int N) {
    __shared__ int sdata[1024];
    int tid = threadIdx.x;
    int j = blockIdx.x * 1024 + tid;
    u32 lo = 0, hi = 0;
    if (j < W) {
        int c = 0;
        for (; c + 8 <= NB; c += 8) {
            u32 w[8];
#pragma unroll
            for (int t = 0; t < 8; t++) w[t] = Hp[(size_t)(c + t) * W + j];
#pragma unroll
            for (int t = 0; t < 8; t++) {
                Hp[(size_t)(c + t) * W + j] = lo | (hi << 16);   // bases fit u16
                lo += w[t] & 0xFFFFu;
                hi += w[t] >> 16;
            }
        }
        for (; c < NB; c++) {
            size_t idx = (size_t)c * W + j;
            u32 w = Hp[idx];
            Hp[idx] = lo | (hi << 16);
            lo += w & 0xFFFFu;
            hi += w >> 16;
        }
    }
    int s = (int)(lo + hi);
    sdata[tid] = s;
    __syncthreads();
    for (int off = 1; off < 1024; off <<= 1) {
        int x = sdata[tid];
        int y = (tid >= off) ? sdata[tid - off] : 0;
        __syncthreads();
        sdata[tid] = x + y;
        __syncthreads();
    }
    int excl = sdata[tid] - s;
    if (j < W) {
        int n0 = 2 * j, n1 = 2 * j + 1;
        offsets[n0] = excl;                         // block-local; scanC adds base
        if (n1 < N) offsets[n1] = excl + (int)lo;
    }
    if (tid == 1023) partials[blockIdx.x] = sdata[1023];
}

// ---- scan phase C: add block bases; set offsets[N] ----
__global__ void scanC_kernel(int* __restrict__ offsets, const int* __restrict__ partials,
                             int M, int E, int nbA) {
    __shared__ int sp[256];
    int tid = threadIdx.x;
    if (tid == 0) {
        int run = 0;
        for (int i = 0; i < nbA; i++) { sp[i] = run; run += partials[i]; }
    }
    __syncthreads();
    int idx = blockIdx.x * blockDim.x + tid;
    if (idx < M) offsets[idx] += sp[idx >> 11];
    if (idx == 0) offsets[M] = E;
}

// ---- scatter: fully atomic-free (pure gathers + one store) ----
__global__ void scatter_kernel(const int* __restrict__ ei, const u32* __restrict__ Hp,
                               const u16* __restrict__ lrank, const int* __restrict__ offsets,
                               u16* __restrict__ srcs, int E, int W) {
    int e = blockIdx.x * blockDim.x + threadIdx.x;
    if (e >= E) return;
    int c = e >> CSHIFT;
    int d = ei[E + e];
    u32 sh = (u32)(d & 1) << 4;
    u32 b = (Hp[(size_t)c * W + (d >> 1)] >> sh) & 0xFFFFu;
    int pos = offsets[d] + (int)b + (int)lrank[e];
    srcs[pos] = (u16)ei[e];
}

// ---- per-node reduction: 4 dims/lane, 2 edges/wave-step, 2 nodes/block ----
__global__ __launch_bounds__(128) void reduce_packed(
        const float* __restrict__ q, const u16* __restrict__ kv,
        const int* __restrict__ offsets, const u16* __restrict__ srcs,
        float* __restrict__ out, int N) {
    int node = blockIdx.x * 2 + (threadIdx.x >> 6);
    if (node >= N) return;
    int l = threadIdx.x & 63;
    int m = l & 31;          // 4-dim group within the row
    int half = l >> 5;       // which edge of the pair this lane handles

    float4 qv = ((const float4*)(q + (long long)node * HID))[m];
    const char* kvb = (const char*)kv;
    u32 laneoff = (u32)m << 4;   // 16B per group
    float4 acc = make_float4(0.0f, 0.0f, 0.0f, 0.0f);
    float z = 0.0f;

    int beg = offsets[node];
    int end = offsets[node + 1];
    int i = beg;

#define GLOAD(s_) (*(const uint4*)(kvb + (((u32)(s_) << 9) + laneoff)))

    for (; i + 8 <= end; i += 8) {
        u32 sA0 = srcs[i + 0], sB0 = srcs[i + 1];
        u32 sA1 = srcs[i + 2], sB1 = srcs[i + 3];
        u32 sA2 = srcs[i + 4], sB2 = srcs[i + 5];
        u32 sA3 = srcs[i + 6], sB3 = srcs[i + 7];
        uint4 a0 = GLOAD(half ? sB0 : sA0);
        uint4 a1 = GLOAD(half ? sB1 : sA1);
        uint4 a2 = GLOAD(half ? sB2 : sA2);
        uint4 a3 = GLOAD(half ? sB3 : sA3);

        float p0 = lof(a0.x) * qv.x + hif(a0.x) * qv.y + lof(a0.z) * qv.z + hif(a0.z) * qv.w;
        float p1 = lof(a1.x) * qv.x + hif(a1.x) * qv.y + lof(a1.z) * qv.z + hif(a1.z) * qv.w;
        float p2 = lof(a2.x) * qv.x + hif(a2.x) * qv.y + lof(a2.z) * qv.z + hif(a2.z) * qv.w;
        float p3 = lof(a3.x) * qv.x + hif(a3.x) * qv.y + lof(a3.z) * qv.z + hif(a3.z) * qv.w;

        p0 += __shfl_xor(p0, 1); p1 += __shfl_xor(p1, 1);
        p2 += __shfl_xor(p2, 1); p3 += __shfl_xor(p3, 1);
        p0 += __shfl_xor(p0, 2); p1 += __shfl_xor(p1, 2);
        p2 += __shfl_xor(p2, 2); p3 += __shfl_xor(p3, 2);

        float c0 = __expf(fminf(fmaxf(p0, -5.0f), 5.0f));
        float c1 = __expf(fminf(fmaxf(p1, -5.0f), 5.0f));
        float c2 = __expf(fminf(fmaxf(p2, -5.0f), 5.0f));
        float c3 = __expf(fminf(fmaxf(p3, -5.0f), 5.0f));

        acc.x += lof(a0.y) * c0 + lof(a1.y) * c1 + lof(a2.y) * c2 + lof(a3.y) * c3;
        acc.y += hif(a0.y) * c0 + hif(a1.y) * c1 + hif(a2.y) * c2 + hif(a3.y) * c3;
        acc.z += lof(a0.w) * c0 + lof(a1.w) * c1 + lof(a2.w) * c2 + lof(a3.w) * c3;
        acc.w += hif(a0.w) * c0 + hif(a1.w) * c1 + hif(a2.w) * c2 + hif(a3.w) * c3;
        z += c0 + c1 + c2 + c3;
    }
    for (; i < end; i += 2) {
        int idx = i + half;
        bool ok = idx < end;
        u32 s = srcs[ok ? idx : i];
        uint4 a = GLOAD(s);
        float p = lof(a.x) * qv.x + hif(a.x) * qv.y + lof(a.z) * qv.z + hif(a.z) * qv.w;
        p += __shfl_xor(p, 1);
        p += __shfl_xor(p, 2);
        float c = __expf(fminf(fmaxf(p, -5.0f), 5.0f));
        c = ok ? c : 0.0f;
        acc.x += lof(a.y) * c;
        acc.y += hif(a.y) * c;
        acc.z += lof(a.w) * c;
        acc.w += hif(a.w) * c;
        z += c;
    }
#undef GLOAD

    acc.x += __shfl_xor(acc.x, 32);
    acc.y += __shfl_xor(acc.y, 32);
    acc.z += __shfl_xor(acc.z, 32);
    acc.w += __shfl_xor(acc.w, 32);
    z     += __shfl_xor(z, 32);

    if (half == 0) {
        float inv = 1.0f / (z + 1e-6f);
        ((float4*)(out + (long long)node * HID))[m] =
            make_float4(acc.x * inv, acc.y * inv, acc.z * inv, acc.w * inv);
    }
}

// ================= fallback path (ws too small / N too large) =================

__global__ void count_kernel(const int* __restrict__ ei, int* __restrict__ counts,
                             int* __restrict__ pos, int E) {
    int e = blockIdx.x * blockDim.x + threadIdx.x;
    if (e < E) pos[e] = atomicAdd(&counts[ei[E + e]], 1);
}

__global__ void fill_kernel(const int* __restrict__ ei, const int* __restrict__ offsets,
                            const int* __restrict__ pos, int* __restrict__ srcs, int E) {
    int e = blockIdx.x * blockDim.x + threadIdx.x;
    if (e < E) srcs[offsets[ei[E + e]] + pos[e]] = ei[e];
}

__global__ __launch_bounds__(256) void reduce_f32(
        const float* __restrict__ q, const float* __restrict__ k,
        const float* __restrict__ v, const int* __restrict__ offsets,
        const int* __restrict__ srcs, float* __restrict__ out, int N) {
    int node = blockIdx.x * 4 + (threadIdx.x >> 6);
    if (node >= N) return;
    int l = threadIdx.x & 63;
    float2 qv = ((const float2*)(q + (long long)node * HID))[l];
    float accx = 0.0f, accy = 0.0f, z = 0.0f;
    int beg = offsets[node], end = offsets[node + 1];
    for (int i = beg; i < end; i++) {
        int s = srcs[i];
        float2 kk = ((const float2*)(k + (long long)s * HID))[l];
        float2 vv = ((const float2*)(v + (long long)s * HID))[l];
        float p = (kk.x * qv.x + kk.y * qv.y) * 0.25f;
        p += __shfl_xor(p, 1);
        p += __shfl_xor(p, 2);
        p += __shfl_xor(p, 4);
        float c = __expf(fminf(fmaxf(p, -5.0f), 5.0f));
        accx += vv.x * c; accy += vv.y * c; z += c;
    }
    float inv = 1.0f / (z + 1e-6f);
    ((float2*)(out + (long long)node * HID))[l] = make_float2(accx * inv, accy * inv);
}

// multi-block scan for fallback (R2 lesson: NEVER single-block over 50K)
__global__ void scanA_kernel(const u32* __restrict__ counts, int* __restrict__ offsets,
                             int* __restrict__ partials, int M) {
    __shared__ int sdata[256];
    int tid = threadIdx.x;
    int base = blockIdx.x * 2048 + tid * 8;
    int v[8];
    int tsum = 0;
    for (int j = 0; j < 8; j++) {
        int idx = base + j;
        v[j] = (idx < M) ? (int)counts[idx] : 0;
        tsum += v[j];
    }
    sdata[tid] = tsum;
    __syncthreads();
    for (int off = 1; off < 256; off <<= 1) {
        int x = sdata[tid];
        int y = (tid >= off) ? sdata[tid - off] : 0;
        __syncthreads();
        sdata[tid] = x + y;
        __syncthreads();
    }
    int excl = sdata[tid] - tsum;
    for (int j = 0; j < 8; j++) {
        int idx = base + j;
        if (idx < M) offsets[idx] = excl;
        excl += v[j];
    }
    if (tid == 255) partials[blockIdx.x] = sdata[255];
}

extern "C" void kernel_launch(void* const* d_in, const int* in_sizes, int n_in,
                              void* d_out, int out_size, void* d_ws, size_t ws_size,
                              hipStream_t stream) {
    const float* q = (const float*)d_in[0];
    const float* k = (const float*)d_in[1];
    const float* v = (const float*)d_in[2];
    const int* ei = (const int*)d_in[3];
    float* out = (float*)d_out;

    int E = in_sizes[3] / 2;      // 800000
    int N = in_sizes[0] / HID;    // 50000

    int eblocks = (E + 255) / 256;
    int nbA = (N + 2047) / 2048;
    int nblocksN = (N + 255) / 256;

    int W = (N + 1) / 2;                          // packed-pair words (25000)
    int NB = (E + CHUNK - 1) >> CSHIFT;           // chunks (49)
    int nbF = (W + 1023) / 1024;                  // fused-scan blocks (25)

    size_t kv_bytes = (size_t)N * 256 * sizeof(u16);
    size_t need = kv_bytes + ((size_t)NB * W + N + 1 + 256) * 4
                + 2 * ((size_t)E + 8) * 2 + 64;

    bool primary = (((W + 1) >> 1) <= WH) && (nbF <= 256) && (ws_size >= need);

    if (primary) {
        u16* kv = (u16*)d_ws;
        u32* Hp = (u32*)((char*)d_ws + kv_bytes);
        int* offsets = (int*)(Hp + (size_t)NB * W);
        int* partials = offsets + N + 1;
        u16* lrank = (u16*)(partials + 256);
        u16* srcs = lrank + ((E + 8) & ~1);

        int histBlocks = NB * 2;                              // 98
        int packBlocks = (N * 64 + 1023) / 1024;              // 3125

        histpack_kernel<<<histBlocks + packBlocks, 1024, 0, stream>>>(
            ei, Hp, lrank, k, v, kv, E, W, N, histBlocks);
        scan_fused_kernel<<<nbF, 1024, 0, stream>>>(Hp, offsets, partials, W, NB, N);
        scanC_kernel<<<nblocksN, 256, 0, stream>>>(offsets, partials, N, E, nbF);
        scatter_kernel<<<eblocks, 256, 0, stream>>>(ei, Hp, lrank, offsets, srcs, E, W);
        int rgrid = (N + 1) / 2;
        reduce_packed<<<rgrid, 128, 0, stream>>>(q, kv, offsets, srcs, out, N);
    } else {
        int* counts = (int*)d_ws;
        int* offsets = counts + N;
        int* partials = offsets + N + 1;
        int* pos = partials + 256;
        int* srcs = pos + E;

        hipMemsetAsync(counts, 0, (size_t)N * sizeof(int), stream);
        count_kernel<<<eblocks, 256, 0, stream>>>(ei, counts, pos, E);
        scanA_kernel<<<nbA, 256, 0, stream>>>((const u32*)counts, offsets, partials, N);
        scanC_kernel<<<nblocksN, 256, 0, stream>>>(offsets, partials, N, E, nbA);
        fill_kernel<<<eblocks, 256, 0, stream>>>(ei, offsets, pos, srcs, E);
        int rgrid = (N + 3) / 4;
        reduce_f32<<<rgrid, 256, 0, stream>>>(q, k, v, offsets, srcs, out, N);
    }
}